// Round 1
// baseline (337.571 us; speedup 1.0000x reference)
//
#include <hip/hip_runtime.h>
#include <hip/hip_bf16.h>

#define N_TOK 32768
#define DIM   192
#define HID   384
#define NEXP  8
#define BM    64
#define TILES_PER_E (N_TOK / BM)   // 512

#define KT1 (DIM/32)   // 6
#define JT1 (HID/16)   // 24
#define KT2 (HID/32)   // 12
#define JT2 (DIM/16)   // 12

#define EPSV 2.220446049250313e-16f

typedef __attribute__((ext_vector_type(8))) short short8;
typedef __attribute__((ext_vector_type(4))) float f32x4;

static __device__ __forceinline__ short f2bf(float f) {
    __hip_bfloat16 h = __float2bfloat16(f);
    return *reinterpret_cast<short*>(&h);
}

// ---------------------------------------------------------------------------
// Gating: logits = [x,emb] @ w_gate ; top-2 ; softmax ; scatter to expert lists
// ---------------------------------------------------------------------------
__global__ __launch_bounds__(256) void gate_kernel(
    const float* __restrict__ x, const float* __restrict__ emb,
    const float* __restrict__ wg,
    int* __restrict__ counts, int* __restrict__ toks, float* __restrict__ gates)
{
    __shared__ float wgs[2 * DIM * NEXP];   // 12 KB
    __shared__ int cnt[NEXP];
    __shared__ int base[NEXP];
    int tid = threadIdx.x;
    for (int i = tid; i < 2 * DIM * NEXP; i += 256) wgs[i] = wg[i];
    if (tid < NEXP) cnt[tid] = 0;
    __syncthreads();

    int t = blockIdx.x * 256 + tid;
    float acc[NEXP];
#pragma unroll
    for (int e = 0; e < NEXP; ++e) acc[e] = 0.f;

    const float4* xp = reinterpret_cast<const float4*>(x + (size_t)t * DIM);
    const float4* ep = reinterpret_cast<const float4*>(emb + (size_t)t * DIM);
#pragma unroll 2
    for (int i = 0; i < DIM / 4; ++i) {
        float4 v = xp[i];
        const float* wr = &wgs[(i * 4) * NEXP];
#pragma unroll
        for (int e = 0; e < NEXP; ++e) acc[e] += v.x * wr[e];
#pragma unroll
        for (int e = 0; e < NEXP; ++e) acc[e] += v.y * wr[NEXP + e];
#pragma unroll
        for (int e = 0; e < NEXP; ++e) acc[e] += v.z * wr[2 * NEXP + e];
#pragma unroll
        for (int e = 0; e < NEXP; ++e) acc[e] += v.w * wr[3 * NEXP + e];
    }
#pragma unroll 2
    for (int i = 0; i < DIM / 4; ++i) {
        float4 v = ep[i];
        const float* wr = &wgs[(DIM + i * 4) * NEXP];
#pragma unroll
        for (int e = 0; e < NEXP; ++e) acc[e] += v.x * wr[e];
#pragma unroll
        for (int e = 0; e < NEXP; ++e) acc[e] += v.y * wr[NEXP + e];
#pragma unroll
        for (int e = 0; e < NEXP; ++e) acc[e] += v.z * wr[2 * NEXP + e];
#pragma unroll
        for (int e = 0; e < NEXP; ++e) acc[e] += v.w * wr[3 * NEXP + e];
    }

    // top-2 (ties -> lowest index, matching jax top_k)
    int i1 = 0; float l1 = acc[0];
#pragma unroll
    for (int e = 1; e < NEXP; ++e) { if (acc[e] > l1) { l1 = acc[e]; i1 = e; } }
    int i2 = -1; float l2 = -1e30f;
#pragma unroll
    for (int e = 0; e < NEXP; ++e) { if (e != i1 && acc[e] > l2) { l2 = acc[e]; i2 = e; } }
    float g1 = 1.f / (1.f + expf(l2 - l1));
    float g2 = 1.f - g1;

    int p1 = atomicAdd(&cnt[i1], 1);
    int p2 = atomicAdd(&cnt[i2], 1);
    __syncthreads();
    if (tid < NEXP) base[tid] = atomicAdd(&counts[tid], cnt[tid]);
    __syncthreads();
    int o1 = base[i1] + p1;
    int o2 = base[i2] + p2;
    toks[i1 * N_TOK + o1]  = (t << 1);
    gates[i1 * N_TOK + o1] = g1;
    toks[i2 * N_TOK + o2]  = (t << 1) | 1;
    gates[i2 * N_TOK + o2] = g2;
}

// ---------------------------------------------------------------------------
// Pack w1/w2 into bf16 MFMA B-fragment order: [e][kt][jt][lane][8elem]
// B-frag layout for mfma_f32_16x16x32_bf16: lane l, elem t -> k=(l>>4)*8+t, j=l&15
// ---------------------------------------------------------------------------
__global__ __launch_bounds__(256) void pack_kernel(
    const float* __restrict__ w1, const float* __restrict__ w2,
    short* __restrict__ pb1, short* __restrict__ pb2)
{
    int i = blockIdx.x * 256 + threadIdx.x;
    const int P1 = NEXP * KT1 * JT1 * 512;   // 589824
    const int P2 = NEXP * KT2 * JT2 * 512;   // 589824
    if (i < P1) {
        int t = i & 7, lane = (i >> 3) & 63;
        int rest = i >> 9;
        int jt = rest % JT1; rest /= JT1;
        int kt = rest % KT1; int e = rest / KT1;
        int k = kt * 32 + (lane >> 4) * 8 + t;
        int j = jt * 16 + (lane & 15);
        pb1[i] = f2bf(w1[((size_t)e * DIM + k) * HID + j]);
    } else if (i < P1 + P2) {
        int i2 = i - P1;
        int t = i2 & 7, lane = (i2 >> 3) & 63;
        int rest = i2 >> 9;
        int jt = rest % JT2; rest /= JT2;
        int kt = rest % KT2; int e = rest / KT2;
        int k = kt * 32 + (lane >> 4) * 8 + t;
        int j = jt * 16 + (lane & 15);
        pb2[i2] = f2bf(w2[((size_t)e * HID + k) * DIM + j]);
    }
}

// ---------------------------------------------------------------------------
// Grouped expert MLP: per 64-token tile of one expert:
//   H = gelu(X @ w1 + b1); Y = H @ w2 + b2; write gate*exp(Y) per (token,slot)
// ---------------------------------------------------------------------------
__global__ __launch_bounds__(256) void expert_kernel(
    const float* __restrict__ x,
    const short* __restrict__ pb1, const short* __restrict__ pb2,
    const float* __restrict__ b1, const float* __restrict__ b2,
    const int* __restrict__ counts, const int* __restrict__ toks,
    const float* __restrict__ gates,
    float* __restrict__ outbuf, int atomic_mode)
{
    int e = blockIdx.x / TILES_PER_E;
    int tile = blockIdx.x - e * TILES_PER_E;
    int cnt = counts[e];
    int m0 = tile * BM;
    if (m0 >= cnt) return;

    // H[64][384] bf16 = 48KB; X[64][192] bf16 reuses the first 24KB (X dead
    // after stage-1 barrier). Both XOR-swizzled: byte ^= (row&7)<<4.
    __shared__ __align__(16) short HX[BM * HID];
    __shared__ float gs[BM];
    __shared__ int   ts[BM];

    int tid = threadIdx.x;
    if (tid < BM) {
        int idx = m0 + tid;
        if (idx < cnt) {
            ts[tid] = toks[e * N_TOK + idx];
            gs[tid] = gates[e * N_TOK + idx];
        } else { ts[tid] = 0; gs[tid] = 0.f; }
    }
    __syncthreads();

    // ---- stage X: gathered rows, fp32 -> bf16, swizzled LDS writes ----
    {
        int r  = tid >> 2;   // row 0..63
        int cs = tid & 3;    // 48-float segment
        int token = ts[r] >> 1;
        const float4* xp = reinterpret_cast<const float4*>(x + (size_t)token * DIM + cs * 48);
        char* xb = reinterpret_cast<char*>(HX);
#pragma unroll
        for (int c = 0; c < 6; ++c) {
            float4 v0 = xp[2 * c], v1 = xp[2 * c + 1];
            short8 s;
            s[0] = f2bf(v0.x); s[1] = f2bf(v0.y); s[2] = f2bf(v0.z); s[3] = f2bf(v0.w);
            s[4] = f2bf(v1.x); s[5] = f2bf(v1.y); s[6] = f2bf(v1.z); s[7] = f2bf(v1.w);
            int byte = r * (DIM * 2) + cs * 96 + c * 16;
            byte ^= (r & 7) << 4;
            *reinterpret_cast<short8*>(xb + byte) = s;
        }
    }
    __syncthreads();

    int wave = tid >> 6, lane = tid & 63;
    int row0 = wave * 16;            // each wave owns 16 rows
    int lrow = lane & 15, lgrp = lane >> 4;
    int arow = row0 + lrow;
    int aswz = (arow & 7) << 4;
    const char* xc = reinterpret_cast<const char*>(HX);
    const f32x4 fzero = {0.f, 0.f, 0.f, 0.f};

    // ---- stage 1: H = X @ w1 ----
    f32x4 acc1[JT1];
#pragma unroll
    for (int j = 0; j < JT1; ++j) acc1[j] = fzero;

    const short8* pb1e = reinterpret_cast<const short8*>(pb1) + (size_t)e * (KT1 * JT1 * 64);
#pragma unroll
    for (int kt = 0; kt < KT1; ++kt) {
        int abyte = arow * (DIM * 2) + (kt * 32 + lgrp * 8) * 2;
        short8 a = *reinterpret_cast<const short8*>(xc + (abyte ^ aswz));
#pragma unroll
        for (int jt = 0; jt < JT1; ++jt) {
            short8 b = pb1e[(kt * JT1 + jt) * 64 + lane];
            acc1[jt] = __builtin_amdgcn_mfma_f32_16x16x32_bf16(a, b, acc1[jt], 0, 0, 0);
        }
    }
    __syncthreads();   // all waves done reading X; H overwrites it

    // ---- gelu(+b1), bf16, to LDS ----
    // D-frag layout: lane l reg r -> row=(l>>4)*4+r, col=l&15 (per-jt +16)
    char* hb = reinterpret_cast<char*>(HX);
#pragma unroll
    for (int jt = 0; jt < JT1; ++jt) {
#pragma unroll
        for (int rr = 0; rr < 4; ++rr) {
            int row = row0 + lgrp * 4 + rr;
            int col = jt * 16 + lrow;
            float h = acc1[jt][rr] + b1[e * HID + col];
            float g = 0.5f * h * (1.f + erff(h * 0.70710678118654752f));
            int byte = (row * (HID * 2) + col * 2) ^ ((row & 7) << 4);
            *reinterpret_cast<short*>(hb + byte) = f2bf(g);
        }
    }
    __syncthreads();

    // ---- stage 2: Y = H @ w2 ----
    f32x4 acc2[JT2];
#pragma unroll
    for (int j = 0; j < JT2; ++j) acc2[j] = fzero;

    const short8* pb2e = reinterpret_cast<const short8*>(pb2) + (size_t)e * (KT2 * JT2 * 64);
#pragma unroll
    for (int kt = 0; kt < KT2; ++kt) {
        int abyte = arow * (HID * 2) + (kt * 32 + lgrp * 8) * 2;
        short8 a = *reinterpret_cast<const short8*>(xc + (abyte ^ aswz));
#pragma unroll
        for (int jt = 0; jt < JT2; ++jt) {
            short8 b = pb2e[(kt * JT2 + jt) * 64 + lane];
            acc2[jt] = __builtin_amdgcn_mfma_f32_16x16x32_bf16(a, b, acc2[jt], 0, 0, 0);
        }
    }

    // ---- epilogue: gate * exp(y) ----
#pragma unroll
    for (int jt = 0; jt < JT2; ++jt) {
#pragma unroll
        for (int rr = 0; rr < 4; ++rr) {
            int row = row0 + lgrp * 4 + rr;
            if (m0 + row < cnt) {
                int col = jt * 16 + lrow;
                float y = acc2[jt][rr] + b2[e * DIM + col];
                float contrib = gs[row] * expf(y);
                int tk = ts[row];
                if (atomic_mode) {
                    atomicAdd(outbuf + (size_t)(tk >> 1) * DIM + col, contrib);
                } else {
                    outbuf[(size_t)tk * DIM + col] = contrib;
                }
            }
        }
    }
}

// ---------------------------------------------------------------------------
// Combine the two slots and take log (slot-buffer path)
// ---------------------------------------------------------------------------
__global__ __launch_bounds__(192) void combine_kernel(
    const float* __restrict__ sb, float* __restrict__ out)
{
    int t = blockIdx.x;
    int j = threadIdx.x;
    float c = sb[(size_t)t * 2 * DIM + j] + sb[(size_t)t * 2 * DIM + DIM + j];
    if (c == 0.f) c = EPSV;
    out[(size_t)t * DIM + j] = logf(c);
}

// In-place log (atomic fallback path)
__global__ __launch_bounds__(256) void log_inplace(float* __restrict__ out, int total)
{
    int i = blockIdx.x * 256 + threadIdx.x;
    if (i < total) {
        float c = out[i];
        out[i] = logf(c == 0.f ? EPSV : c);
    }
}

// ---------------------------------------------------------------------------
extern "C" void kernel_launch(void* const* d_in, const int* in_sizes, int n_in,
                              void* d_out, int out_size, void* d_ws, size_t ws_size,
                              hipStream_t stream) {
    const float* x   = (const float*)d_in[0];
    const float* emb = (const float*)d_in[1];
    const float* wg  = (const float*)d_in[2];
    const float* w1  = (const float*)d_in[3];
    const float* b1  = (const float*)d_in[4];
    const float* w2  = (const float*)d_in[5];
    const float* b2  = (const float*)d_in[6];
    float* out = (float*)d_out;

    char* ws = (char*)d_ws;
    size_t off = 0;
    int*   counts = (int*)(ws + off);   off += 256;
    int*   toks   = (int*)(ws + off);   off += (size_t)NEXP * N_TOK * 4;
    float* gates  = (float*)(ws + off); off += (size_t)NEXP * N_TOK * 4;
    short* pb1    = (short*)(ws + off); off += (size_t)NEXP * KT1 * JT1 * 512 * 2;
    short* pb2    = (short*)(ws + off); off += (size_t)NEXP * KT2 * JT2 * 512 * 2;
    size_t slotoff = (off + 255) & ~(size_t)255;
    float* slotbuf = (float*)(ws + slotoff);
    size_t need_slot = slotoff + (size_t)N_TOK * 2 * DIM * 4;
    int atomic_mode = (ws_size >= need_slot) ? 0 : 1;

    hipMemsetAsync(counts, 0, NEXP * sizeof(int), stream);
    if (atomic_mode) hipMemsetAsync(out, 0, (size_t)out_size * 4, stream);

    pack_kernel<<<(NEXP * KT1 * JT1 * 512 + NEXP * KT2 * JT2 * 512) / 256, 256, 0, stream>>>(w1, w2, pb1, pb2);
    gate_kernel<<<N_TOK / 256, 256, 0, stream>>>(x, emb, wg, counts, toks, gates);

    float* target = atomic_mode ? out : slotbuf;
    expert_kernel<<<NEXP * TILES_PER_E, 256, 0, stream>>>(
        x, pb1, pb2, b1, b2, counts, toks, gates, target, atomic_mode);

    if (atomic_mode) {
        log_inplace<<<(N_TOK * DIM + 255) / 256, 256, 0, stream>>>(out, N_TOK * DIM);
    } else {
        combine_kernel<<<N_TOK, 192, 0, stream>>>(slotbuf, out);
    }
}

// Round 2
// 245.246 us; speedup vs baseline: 1.3765x; 1.3765x over previous
//
#include <hip/hip_runtime.h>
#include <hip/hip_bf16.h>

#define N_TOK 32768
#define DIM   192
#define HID   384
#define NEXP  8
#define BM    64
#define TILES_PER_E (N_TOK / BM)   // 512

#define KT1 6     // DIM/32
#define JT1 24    // HID/16
#define KT2 12    // HID/32
#define JT2 12    // DIM/16

#define EPSV 2.220446049250313e-16f

typedef __attribute__((ext_vector_type(8))) short short8;
typedef __attribute__((ext_vector_type(4))) short short4v;
typedef __attribute__((ext_vector_type(4))) float f32x4;

static __device__ __forceinline__ short f2bf(float f) {
    union { __hip_bfloat16 h; short s; } u;
    u.h = __float2bfloat16(f);
    return u.s;
}

typedef const __attribute__((address_space(1))) void* gptr_t;
typedef __attribute__((address_space(3))) void* lptr_t;
#define GLOAD_LDS16(g, l) \
    __builtin_amdgcn_global_load_lds((gptr_t)(const void*)(g), (lptr_t)(void*)(l), 16, 0, 0)

// stage 24576 B (one BK=32 w1 slice, or two BK=32 w2 slices) global -> LDS
static __device__ __forceinline__ void stage24k(const char* __restrict__ src, char* dst,
                                                int wave, int lane) {
#pragma unroll
    for (int i = 0; i < 6; ++i) {
        int off = i * 4096 + wave * 1024;
        GLOAD_LDS16(src + off + lane * 16, dst + off);
    }
}

// ---------------------------------------------------------------------------
// Gating: logits = [x,emb] @ w_gate ; top-2 ; softmax ; scatter to expert lists.
// Also (optionally) emits x as bf16 rows for the expert GEMM A-operand.
// ---------------------------------------------------------------------------
template<bool WXB>
__global__ __launch_bounds__(256) void gate_kernel(
    const float* __restrict__ x, const float* __restrict__ emb,
    const float* __restrict__ wg,
    int* __restrict__ counts, int* __restrict__ toks, float* __restrict__ gates,
    short* __restrict__ xb)
{
    __shared__ float wgs[2 * DIM * NEXP];   // 12 KB
    __shared__ int cnt[NEXP];
    __shared__ int base[NEXP];
    int tid = threadIdx.x;
    for (int i = tid; i < 2 * DIM * NEXP; i += 256) wgs[i] = wg[i];
    if (tid < NEXP) cnt[tid] = 0;
    __syncthreads();

    int t = blockIdx.x * 256 + tid;
    float acc[NEXP];
#pragma unroll
    for (int e = 0; e < NEXP; ++e) acc[e] = 0.f;

    const float4* xp = reinterpret_cast<const float4*>(x + (size_t)t * DIM);
    const float4* ep = reinterpret_cast<const float4*>(emb + (size_t)t * DIM);
    short* xrow = WXB ? (xb + (size_t)t * DIM) : nullptr;
#pragma unroll 2
    for (int i = 0; i < DIM / 4; ++i) {
        float4 v = xp[i];
        if (WXB) {
            short4v s; s[0] = f2bf(v.x); s[1] = f2bf(v.y); s[2] = f2bf(v.z); s[3] = f2bf(v.w);
            *reinterpret_cast<short4v*>(xrow + i * 4) = s;
        }
        const float* wr = &wgs[(i * 4) * NEXP];
#pragma unroll
        for (int e = 0; e < NEXP; ++e) acc[e] += v.x * wr[e];
#pragma unroll
        for (int e = 0; e < NEXP; ++e) acc[e] += v.y * wr[NEXP + e];
#pragma unroll
        for (int e = 0; e < NEXP; ++e) acc[e] += v.z * wr[2 * NEXP + e];
#pragma unroll
        for (int e = 0; e < NEXP; ++e) acc[e] += v.w * wr[3 * NEXP + e];
    }
#pragma unroll 2
    for (int i = 0; i < DIM / 4; ++i) {
        float4 v = ep[i];
        const float* wr = &wgs[(DIM + i * 4) * NEXP];
#pragma unroll
        for (int e = 0; e < NEXP; ++e) acc[e] += v.x * wr[e];
#pragma unroll
        for (int e = 0; e < NEXP; ++e) acc[e] += v.y * wr[NEXP + e];
#pragma unroll
        for (int e = 0; e < NEXP; ++e) acc[e] += v.z * wr[2 * NEXP + e];
#pragma unroll
        for (int e = 0; e < NEXP; ++e) acc[e] += v.w * wr[3 * NEXP + e];
    }

    int i1 = 0; float l1 = acc[0];
#pragma unroll
    for (int e = 1; e < NEXP; ++e) { if (acc[e] > l1) { l1 = acc[e]; i1 = e; } }
    int i2 = -1; float l2 = -1e30f;
#pragma unroll
    for (int e = 0; e < NEXP; ++e) { if (e != i1 && acc[e] > l2) { l2 = acc[e]; i2 = e; } }
    float g1 = 1.f / (1.f + expf(l2 - l1));
    float g2 = 1.f - g1;

    int p1 = atomicAdd(&cnt[i1], 1);
    int p2 = atomicAdd(&cnt[i2], 1);
    __syncthreads();
    if (tid < NEXP) base[tid] = atomicAdd(&counts[tid], cnt[tid]);
    __syncthreads();
    int o1 = base[i1] + p1;
    int o2 = base[i2] + p2;
    toks[i1 * N_TOK + o1]  = (t << 1);
    gates[i1 * N_TOK + o1] = g1;
    toks[i2 * N_TOK + o2]  = (t << 1) | 1;
    gates[i2 * N_TOK + o2] = g2;
}

// ---------------------------------------------------------------------------
// Pack w1/w2 -> bf16 MFMA B-fragment order [e][kt][jt][lane][8].
// Coalesced float4 source reads; scattered 2B writes (fire-and-forget).
// frag elem (k,j): kt=k>>5, jt=j>>4, lane=(j&15)|(((k>>3)&3)<<4), t=k&7
// ---------------------------------------------------------------------------
__global__ __launch_bounds__(256) void pack_kernel(
    const float* __restrict__ w1, const float* __restrict__ w2,
    short* __restrict__ pb1, short* __restrict__ pb2)
{
    const int Q = NEXP * DIM * HID / 4;   // 147456 threads per tensor
    int i = blockIdx.x * 256 + threadIdx.x;
    if (i < Q) {
        int idx = i * 4;
        int e = idx / (DIM * HID);
        int r = idx - e * (DIM * HID);
        int k = r / HID, j0 = r - k * HID;
        float4 v = *reinterpret_cast<const float4*>(w1 + idx);
        const float* vp = reinterpret_cast<const float*>(&v);
        int lg = (k >> 3) & 3, tt = k & 7;
        short* base = pb1 + ((size_t)(e * KT1 + (k >> 5)) * JT1) * 512;
#pragma unroll
        for (int d = 0; d < 4; ++d) {
            int j = j0 + d;
            base[(j >> 4) * 512 + (((j & 15) | (lg << 4)) << 3) + tt] = f2bf(vp[d]);
        }
    } else if (i < 2 * Q) {
        int idx = (i - Q) * 4;
        int e = idx / (HID * DIM);
        int r = idx - e * (HID * DIM);
        int k = r / DIM, j0 = r - k * DIM;
        float4 v = *reinterpret_cast<const float4*>(w2 + idx);
        const float* vp = reinterpret_cast<const float*>(&v);
        int lg = (k >> 3) & 3, tt = k & 7;
        short* base = pb2 + ((size_t)(e * KT2 + (k >> 5)) * JT2) * 512;
#pragma unroll
        for (int d = 0; d < 4; ++d) {
            int j = j0 + d;
            base[(j >> 4) * 512 + (((j & 15) | (lg << 4)) << 3) + tt] = f2bf(vp[d]);
        }
    }
}

// ---------------------------------------------------------------------------
// Pass 1: H[tk] = gelu(x[tok] @ w1[e] + b1[e])   (bf16 rows, 768 B each)
// w1 slices LDS-double-buffered via global_load_lds; A-frags straight from global.
// ---------------------------------------------------------------------------
template<bool USE_XB>
__global__ __launch_bounds__(256) void h_kernel(
    const float* __restrict__ x, const short* __restrict__ xb,
    const short* __restrict__ pb1, const float* __restrict__ b1,
    const int* __restrict__ counts, const int* __restrict__ toks,
    short* __restrict__ H)
{
    int e = blockIdx.x / TILES_PER_E;
    int tile = blockIdx.x - e * TILES_PER_E;
    int cnt = counts[e];
    int m0 = tile * BM;
    if (m0 >= cnt) return;

    __shared__ __align__(16) char wlds[2 * 24576];   // 48 KB dbuf
    __shared__ int ts[BM];

    int tid = threadIdx.x;
    int wave = tid >> 6, lane = tid & 63;
    const char* pb1e = reinterpret_cast<const char*>(pb1) + (size_t)e * (KT1 * 24576);

    if (tid < BM) {
        int idx = m0 + tid;
        ts[tid] = (idx < cnt) ? toks[e * N_TOK + idx] : 0;
    }
    stage24k(pb1e, wlds, wave, lane);
    __syncthreads();    // ts visible + stage(0) drained by all threads

    int lrow = lane & 15, lgrp = lane >> 4;
    int row0 = wave * 16;
    int tok = ts[row0 + lrow] >> 1;

    short8 afrag[KT1];
    if (USE_XB) {
        const char* xr = reinterpret_cast<const char*>(xb) + (size_t)tok * 384 + lgrp * 16;
#pragma unroll
        for (int kt = 0; kt < KT1; ++kt)
            afrag[kt] = *reinterpret_cast<const short8*>(xr + kt * 64);
    } else {
        const char* xr = reinterpret_cast<const char*>(x) + (size_t)tok * 768 + lgrp * 32;
#pragma unroll
        for (int kt = 0; kt < KT1; ++kt) {
            float4 a0 = *reinterpret_cast<const float4*>(xr + kt * 128);
            float4 a1 = *reinterpret_cast<const float4*>(xr + kt * 128 + 16);
            short8 s;
            s[0] = f2bf(a0.x); s[1] = f2bf(a0.y); s[2] = f2bf(a0.z); s[3] = f2bf(a0.w);
            s[4] = f2bf(a1.x); s[5] = f2bf(a1.y); s[6] = f2bf(a1.z); s[7] = f2bf(a1.w);
            afrag[kt] = s;
        }
    }
    stage24k(pb1e + 24576, wlds + 24576, wave, lane);   // prefetch slice 1

    f32x4 acc[JT1];
#pragma unroll
    for (int j = 0; j < JT1; ++j) acc[j] = (f32x4){0.f, 0.f, 0.f, 0.f};

#pragma unroll
    for (int kt = 0; kt < KT1; ++kt) {
        if (kt > 0) {
            asm volatile("s_waitcnt vmcnt(0)" ::: "memory");  // stage(kt) landed
            __builtin_amdgcn_s_barrier();                      // all threads landed; prev reads done
            __builtin_amdgcn_sched_barrier(0);
            if (kt < KT1 - 1)
                stage24k(pb1e + (size_t)(kt + 1) * 24576, wlds + ((kt + 1) & 1) * 24576, wave, lane);
        }
        const char* wb = wlds + (kt & 1) * 24576;
#pragma unroll
        for (int jt = 0; jt < JT1; ++jt) {
            short8 b = *reinterpret_cast<const short8*>(wb + jt * 1024 + lane * 16);
            acc[jt] = __builtin_amdgcn_mfma_f32_16x16x32_bf16(afrag[kt], b, acc[jt], 0, 0, 0);
        }
    }

    // epilogue: gelu(+b1) -> bf16 row-major H
    const float* b1e = b1 + e * HID;
    int r0 = row0 + lgrp * 4;
#pragma unroll
    for (int rr = 0; rr < 4; ++rr) {
        int lr = r0 + rr;
        if (m0 + lr < cnt) {
            short* hrow = H + (size_t)ts[lr] * HID;
#pragma unroll
            for (int jt = 0; jt < JT1; ++jt) {
                int col = jt * 16 + lrow;
                float h = acc[jt][rr] + b1e[col];
                float g = 0.5f * h * (1.f + erff(h * 0.70710678118654752f));
                hrow[col] = f2bf(g);
            }
        }
    }
}

// ---------------------------------------------------------------------------
// Pass 2: slot[tk] = gate * exp(H[tk] @ w2[e] + b2[e])  (fp32, overwrites H rows)
// ---------------------------------------------------------------------------
__global__ __launch_bounds__(256) void y_kernel(
    const short* __restrict__ H,
    const short* __restrict__ pb2, const float* __restrict__ b2,
    const int* __restrict__ counts, const int* __restrict__ toks,
    const float* __restrict__ gates,
    float* __restrict__ slot)
{
    int e = blockIdx.x / TILES_PER_E;
    int tile = blockIdx.x - e * TILES_PER_E;
    int cnt = counts[e];
    int m0 = tile * BM;
    if (m0 >= cnt) return;

    __shared__ __align__(16) char wlds[2 * 24576];   // each buf: two BK=32 slices
    __shared__ int ts[BM];
    __shared__ float gs[BM];

    int tid = threadIdx.x;
    int wave = tid >> 6, lane = tid & 63;
    const char* pb2e = reinterpret_cast<const char*>(pb2) + (size_t)e * (KT2 * 12288);

    if (tid < BM) {
        int idx = m0 + tid;
        ts[tid] = (idx < cnt) ? toks[e * N_TOK + idx] : 0;
        gs[tid] = (idx < cnt) ? gates[e * N_TOK + idx] : 0.f;
    }
    stage24k(pb2e, wlds, wave, lane);
    __syncthreads();

    int lrow = lane & 15, lgrp = lane >> 4;
    int row0 = wave * 16;
    int tka = ts[row0 + lrow];

    short8 afrag[KT2];
    {
        const char* hr = reinterpret_cast<const char*>(H) + (size_t)tka * 768 + lgrp * 16;
#pragma unroll
        for (int kt = 0; kt < KT2; ++kt)
            afrag[kt] = *reinterpret_cast<const short8*>(hr + kt * 64);
    }
    stage24k(pb2e + 24576, wlds + 24576, wave, lane);

    f32x4 acc[JT2];
#pragma unroll
    for (int j = 0; j < JT2; ++j) acc[j] = (f32x4){0.f, 0.f, 0.f, 0.f};

#pragma unroll
    for (int p = 0; p < 6; ++p) {
        if (p > 0) {
            asm volatile("s_waitcnt vmcnt(0)" ::: "memory");
            __builtin_amdgcn_s_barrier();
            __builtin_amdgcn_sched_barrier(0);
            if (p < 5)
                stage24k(pb2e + (size_t)(p + 1) * 24576, wlds + ((p + 1) & 1) * 24576, wave, lane);
        }
        const char* buf = wlds + (p & 1) * 24576;
#pragma unroll
        for (int kk = 0; kk < 2; ++kk) {
            int kt = p * 2 + kk;
            const char* wb = buf + kk * 12288;
#pragma unroll
            for (int jt = 0; jt < JT2; ++jt) {
                short8 b = *reinterpret_cast<const short8*>(wb + jt * 1024 + lane * 16);
                acc[jt] = __builtin_amdgcn_mfma_f32_16x16x32_bf16(afrag[kt], b, acc[jt], 0, 0, 0);
            }
        }
    }

    const float* b2e = b2 + e * DIM;
    int r0 = row0 + lgrp * 4;
#pragma unroll
    for (int rr = 0; rr < 4; ++rr) {
        int lr = r0 + rr;
        if (m0 + lr < cnt) {
            float g = gs[lr];
            float* srow = slot + (size_t)ts[lr] * DIM;
#pragma unroll
            for (int jt = 0; jt < JT2; ++jt) {
                int col = jt * 16 + lrow;
                float y = acc[jt][rr] + b2e[col];
                srow[col] = g * expf(y);
            }
        }
    }
}

// ---------------------------------------------------------------------------
// out[t][:] = log(slot[2t][:] + slot[2t+1][:])   (vectorized)
// ---------------------------------------------------------------------------
__global__ __launch_bounds__(256) void combine_kernel(
    const float* __restrict__ sb, float* __restrict__ out)
{
    int i = blockIdx.x * 256 + threadIdx.x;   // over N_TOK*DIM/4
    int t = i / 48;
    int j = (i - t * 48) * 4;
    const float* r = sb + (size_t)t * (2 * DIM);
    float4 a = *reinterpret_cast<const float4*>(r + j);
    float4 b = *reinterpret_cast<const float4*>(r + DIM + j);
    float4 o;
    float c;
    c = a.x + b.x; o.x = logf(c == 0.f ? EPSV : c);
    c = a.y + b.y; o.y = logf(c == 0.f ? EPSV : c);
    c = a.z + b.z; o.z = logf(c == 0.f ? EPSV : c);
    c = a.w + b.w; o.w = logf(c == 0.f ? EPSV : c);
    *reinterpret_cast<float4*>(out + (size_t)i * 4) = o;
}

// ---------------------------------------------------------------------------
extern "C" void kernel_launch(void* const* d_in, const int* in_sizes, int n_in,
                              void* d_out, int out_size, void* d_ws, size_t ws_size,
                              hipStream_t stream) {
    const float* x   = (const float*)d_in[0];
    const float* emb = (const float*)d_in[1];
    const float* wg  = (const float*)d_in[2];
    const float* w1  = (const float*)d_in[3];
    const float* b1  = (const float*)d_in[4];
    const float* w2  = (const float*)d_in[5];
    const float* b2  = (const float*)d_in[6];
    float* out = (float*)d_out;

    char* ws = (char*)d_ws;
    size_t off = 0;
    auto alloc = [&](size_t n) { size_t p = off; off = (off + n + 255) & ~(size_t)255; return p; };
    int*   counts = (int*)  (ws + alloc(256));
    int*   toks   = (int*)  (ws + alloc((size_t)NEXP * N_TOK * 4));
    float* gates  = (float*)(ws + alloc((size_t)NEXP * N_TOK * 4));
    short* pb1    = (short*)(ws + alloc((size_t)NEXP * DIM * HID * 2));
    short* pb2    = (short*)(ws + alloc((size_t)NEXP * HID * DIM * 2));
    size_t hoff   = alloc((size_t)2 * N_TOK * HID * 2);   // H bf16 rows == slot fp32 rows
    short* Hbuf   = (short*)(ws + hoff);
    float* slotf  = (float*)(ws + hoff);
    size_t xoff   = alloc((size_t)N_TOK * DIM * 2);
    short* xb     = (short*)(ws + xoff);
    bool use_xb = (ws_size >= off);

    hipMemsetAsync(counts, 0, NEXP * sizeof(int), stream);

    const int Q = NEXP * DIM * HID / 4;
    pack_kernel<<<(2 * Q) / 256, 256, 0, stream>>>(w1, w2, pb1, pb2);

    if (use_xb)
        gate_kernel<true><<<N_TOK / 256, 256, 0, stream>>>(x, emb, wg, counts, toks, gates, xb);
    else
        gate_kernel<false><<<N_TOK / 256, 256, 0, stream>>>(x, emb, wg, counts, toks, gates, nullptr);

    if (use_xb)
        h_kernel<true><<<NEXP * TILES_PER_E, 256, 0, stream>>>(x, xb, pb1, b1, counts, toks, Hbuf);
    else
        h_kernel<false><<<NEXP * TILES_PER_E, 256, 0, stream>>>(x, nullptr, pb1, b1, counts, toks, Hbuf);

    y_kernel<<<NEXP * TILES_PER_E, 256, 0, stream>>>(Hbuf, pb2, b2, counts, toks, gates, slotf);

    combine_kernel<<<(N_TOK * DIM / 4) / 256, 256, 0, stream>>>(slotf, out);
}